// Round 14
// baseline (9588.618 us; speedup 1.0000x reference)
//
#include <hip/hip_runtime.h>
#include <cstdint>
#include <cstddef>

typedef _Float16 half_t;
typedef half_t half2_t __attribute__((ext_vector_type(2)));
typedef _Float16 half8 __attribute__((ext_vector_type(8)));
typedef unsigned uint4v __attribute__((ext_vector_type(4)));
typedef float float4v __attribute__((ext_vector_type(4)));

static constexpr int TTs = 2048;   // timesteps
static constexpr int BBn = 64;     // batch
static constexpr int DINn = 64;    // input dim
static constexpr int HPn  = 256;   // proj dim
static constexpr int U0c = 135, C0c = 391, R0c = 405;   // layer0
static constexpr int U1c = 89,  C1c = 224, R1c = 267;   // layer1
static constexpr int U2c = 32,  C2c = 121, R2c = 96;    // layer2
static constexpr size_t BTn = (size_t)BBn * TTs;        // 131072
static constexpr int NFRAG = 339;  // w0-6: 42 each; w7: 45 (21 L1 + 24 L2)

// ---------------- math helpers ----------------
__device__ __forceinline__ float tanh_f(float x) {
    return 1.f - __fdividef(2.f, __expf(2.f * x) + 1.f);
}
__device__ __forceinline__ float sigm_f(float x) {
    return __fdividef(1.f, 1.f + __expf(-x));
}
__device__ __forceinline__ float cfc_comb(float y0, float y1, float y2) {
    float f1 = tanh_f(y0), f2 = tanh_f(y1), ti = sigm_f(y2);
    return f1 + ti * (f2 - f1);
}

// ---------------- mask dtype probe ----------------
__device__ __forceinline__ int mask_mode(const unsigned char* mp) {
    const unsigned* wp = (const unsigned*)mp;
    bool all01 = true, allf = true;
    for (int k = 0; k < 64; ++k) {
        unsigned w = wp[k];
        all01 = all01 && (w == 0u || w == 1u);
        allf  = allf  && (w == 0u || w == 0x3F800000u);
    }
    if (all01) return 0;
    if (allf)  return 1;
    return 2;
}
__device__ __forceinline__ bool mget(const unsigned char* mp, int mode, int idx) {
    if (mode == 0) return ((const int*)mp)[idx] != 0;
    if (mode == 1) return ((const float*)mp)[idx] != 0.f;
    return mp[idx] != 0;
}

// ---------------- prep: stack + mask weights ----------------
__global__ void k_stack(const float* __restrict__ Wff1, const float* __restrict__ bff1,
                        const float* __restrict__ Wff2, const float* __restrict__ bff2,
                        const float* __restrict__ Wta,  const float* __restrict__ bta,
                        const float* __restrict__ Wtb,  const float* __restrict__ btb,
                        const unsigned char* __restrict__ maskraw,
                        int u, int c, int split,
                        float* __restrict__ outA, float* __restrict__ outB,
                        float* __restrict__ bias_out)
{
    const int mode = mask_mode(maskraw);
    const int total = 3 * u * c + 3 * u;
    for (int idx = blockIdx.x * blockDim.x + threadIdx.x; idx < total;
         idx += gridDim.x * blockDim.x) {
        if (idx < 3 * u * c) {
            int m = idx / (u * c);
            int rem = idx - m * u * c;
            int r = rem / c;
            int k = rem - r * c;
            float v;
            if (m == 2) {
                v = Wta[r * c + k] + Wtb[r * c + k];
            } else {
                bool mk = mget(maskraw, mode, r * c + k);
                float w = (m == 0) ? Wff1[r * c + k] : Wff2[r * c + k];
                v = mk ? w : 0.f;
            }
            int R = m * u + r;
            if (k < split) outA[(size_t)R * split + k] = v;
            else           outB[(size_t)R * (c - split) + (k - split)] = v;
        } else {
            int j = idx - 3 * u * c;
            int m = j / u, r = j - m * u;
            bias_out[j] = (m == 0) ? bff1[r] : ((m == 1) ? bff2[r] : (bta[r] + btb[r]));
        }
    }
}

// ---------------- prep: Wcomb = Wx0s (405x256) @ Wp (256x64) ----------------
__global__ void k_comb(const float* __restrict__ Wx0s, const float* __restrict__ Wp,
                       float* __restrict__ Wcomb)
{
    const int r = blockIdx.x;
    const int d = threadIdx.x;
    float acc = 0.f;
    for (int k = 0; k < HPn; ++k) acc += Wx0s[(size_t)r * HPn + k] * Wp[(size_t)k * DINn + d];
    Wcomb[(size_t)r * DINn + d] = acc;
}

// ---------------- prep: folded bias + Wh2 transpose ----------------
__global__ void k_biasc(const float* __restrict__ Wx0s, const float* __restrict__ bp,
                        const float* __restrict__ b0, float* __restrict__ b0c,
                        const float* __restrict__ Wh2, float* __restrict__ Wh2T)
{
    const int i = blockIdx.x * blockDim.x + threadIdx.x;
    if (i < R0c) {
        float a = b0[i];
        for (int k = 0; k < HPn; ++k) a += Wx0s[(size_t)i * HPn + k] * bp[k];
        b0c[i] = a;
    }
    if (i < HPn * 32) {
        int h = i >> 5, o = i & 31;
        Wh2T[i] = Wh2[(size_t)o * HPn + h];
    }
}

// ---------------- prep: pack weights to padded fp16 row-major ----------------
// W0h (405,224): [Wcb:64 | Wh0s:135 | 0:25]; W1h (267,224); W2h (96,128): [W2s:121|0:7]
__global__ void k_pack(const float* __restrict__ Wcb, const float* __restrict__ Wh0s,
                       const float* __restrict__ W1s, const float* __restrict__ W2s,
                       half_t* __restrict__ W0h, half_t* __restrict__ W1h,
                       half_t* __restrict__ W2h)
{
    const int N0 = R0c * 224, N1 = R1c * 224, N2 = R2c * 128;
    for (int idx = blockIdx.x * blockDim.x + threadIdx.x; idx < N0 + N1 + N2;
         idx += gridDim.x * blockDim.x) {
        if (idx < N0) {
            int r = idx / 224, c = idx - r * 224;
            float v = (c < 64) ? Wcb[(size_t)r * 64 + c]
                               : ((c < 199) ? Wh0s[(size_t)r * 135 + (c - 64)] : 0.f);
            W0h[idx] = (half_t)v;
        } else if (idx < N0 + N1) {
            int i = idx - N0;
            W1h[i] = (half_t)W1s[i];
        } else {
            int i = idx - N0 - N1;
            int r = i / 128, c = i - r * 128;
            W2h[i] = (half_t)((c < 121) ? W2s[(size_t)r * 121 + c] : 0.f);
        }
    }
}

// ---------------- prep: MFMA A-fragment packing, mod-16-aligned groups ------
// Wave assignment (42 frags w0-6, 45 w7):
//  w0..w3: L0 groups {2w, 2w+1}; w4: L0 g8 + L1 g0; w5: L1 {1,2}; w6: L1 {3,4};
//  w7: L1 g5 + L2 {0,1}.
// Per group: 3 gate tiles (rows 16g..16g+15 of each gate section), K-steps.
// A layout (r12-verified): lane l -> row = 16g + (l&15), col = kk*32 + ((l>>4)&3)*8 + j.
// Bias folded in K: L0 col 199 <- b0c; L2 col 121 <- b2s. L1 bias handled in combine.
__global__ __launch_bounds__(256) void k_frag(const half_t* __restrict__ W0h,
                                              const half_t* __restrict__ W1h,
                                              const half_t* __restrict__ W2h,
                                              const float* __restrict__ b0c,
                                              const float* __restrict__ b2s,
                                              half_t* __restrict__ Wf)
{
    int idx = blockIdx.x * 256 + threadIdx.x;
    if (idx >= NFRAG * 64) return;
    int fid = idx >> 6, l = idx & 63;
    int mat, g, m, kk;
    if (fid < 294) {
        int w = fid / 42, r = fid - w * 42;
        int gi = r / 21, rr = r - gi * 21;
        m = rr / 7; kk = rr - m * 7;
        if (w < 4)       { mat = 0; g = 2 * w + gi; }
        else if (w == 4) { if (gi == 0) { mat = 0; g = 8; } else { mat = 1; g = 0; } }
        else if (w == 5) { mat = 1; g = 1 + gi; }
        else             { mat = 1; g = 3 + gi; }
    } else {
        int r = fid - 294;
        if (r < 21) { mat = 1; g = 5; m = r / 7; kk = r - m * 7; }
        else { int rr = r - 21; g = rr / 12; int r2 = rr - g * 12; mat = 2;
               m = r2 / 4; kk = r2 - m * 4; }
    }
    int u = 16 * g + (l & 15);
    int c0 = kk * 32 + ((l >> 4) & 3) * 8;
    half_t v[8];
#pragma unroll
    for (int j = 0; j < 8; ++j) v[j] = (half_t)0.f;
    if (mat == 0) {
        if (u < U0c) {
            const half_t* rp = W0h + (size_t)(m * U0c + u) * 224 + c0;
#pragma unroll
            for (int j = 0; j < 8; ++j) v[j] = rp[j];
            if (c0 <= 199 && 199 < c0 + 8) v[199 - c0] = (half_t)b0c[m * U0c + u];
        }
    } else if (mat == 1) {
        if (u < U1c) {
            const half_t* rp = W1h + (size_t)(m * U1c + u) * 224 + c0;
#pragma unroll
            for (int j = 0; j < 8; ++j) v[j] = rp[j];
        }
    } else {
        const half_t* rp = W2h + (size_t)(m * U2c + u) * 128 + c0;
#pragma unroll
        for (int j = 0; j < 8; ++j) v[j] = rp[j];
        if (c0 <= 121 && 121 < c0 + 8) v[121 - c0] = (half_t)b2s[m * U2c + u];
    }
    half_t* dst = Wf + ((size_t)fid * 64 + l) * 8;
#pragma unroll
    for (int j = 0; j < 8; ++j) dst[j] = v[j];
}

// ---------------- prep: x fp32 -> fp16 ----------------
__global__ __launch_bounds__(256) void k_xh(const float* __restrict__ x,
                                            half_t* __restrict__ xh)
{
    size_t i = ((size_t)blockIdx.x * 256 + threadIdx.x) * 4;
    if (i >= BTn * (size_t)DINn) return;
    float4 v = *(const float4*)(x + i);
    half_t* o = xh + i;
    o[0] = (half_t)v.x; o[1] = (half_t)v.y; o[2] = (half_t)v.z; o[3] = (half_t)v.w;
}

// light barrier: LDS-ordering only; vmem stays in flight.
#define BAR() asm volatile("s_waitcnt lgkmcnt(0)\n\ts_barrier" ::: "memory")

#define MF(ACC, A, BB) (ACC) = __builtin_amdgcn_mfma_f32_16x16x32_f16( \
    __builtin_bit_cast(half8, (A)), __builtin_bit_cast(half8, (BB)), (ACC), 0, 0, 0);

#define CH7(ACC, A0,A1,A2,A3,A4,A5,A6) float4v ACC = (float4v)0.0f; \
    MF(ACC,A0,B0) MF(ACC,A1,B1) MF(ACC,A2,B2) MF(ACC,A3,B3) \
    MF(ACC,A4,B4) MF(ACC,A5,B5) MF(ACC,A6,B6)
#define CH4(ACC, A0,A1,A2,A3) float4v ACC = (float4v)0.0f; \
    MF(ACC,A0,B0) MF(ACC,A1,B1) MF(ACC,A2,B2) MF(ACC,A3,B3)

// L0 group: 21 MFMA + in-lane combine -> h0^{k+1}
#define L0G(G, F0,F1,F2,F3,F4,F5,F6,F7,F8,F9,F10,F11,F12,F13,F14,F15,F16,F17,F18,F19,F20) { \
    CH7(aA, F0,F1,F2,F3,F4,F5,F6) \
    CH7(aB, F7,F8,F9,F10,F11,F12,F13) \
    CH7(aC, F14,F15,F16,F17,F18,F19,F20) \
    if (wr0) { \
        _Pragma("unroll") \
        for (int j = 0; j < 4; ++j) { \
            int u = 16 * (G) + q4 * 4 + j; \
            if (u < U0c) { \
                float hv = cfc_comb(aA[j], aB[j], aC[j]); \
                half_t hh = (half_t)hv; \
                z0n[64 + u] = hh; z1n[u] = hh; } } } }

// L1 group: 21 MFMA + in-lane combine (biases from LDS) -> h1^k, gated k>=1
#define L1G(G, F0,F1,F2,F3,F4,F5,F6,F7,F8,F9,F10,F11,F12,F13,F14,F15,F16,F17,F18,F19,F20) { \
    CH7(aA, F0,F1,F2,F3,F4,F5,F6) \
    CH7(aB, F7,F8,F9,F10,F11,F12,F13) \
    CH7(aC, F14,F15,F16,F17,F18,F19,F20) \
    if (wr0 && k >= 1) { \
        _Pragma("unroll") \
        for (int j = 0; j < 4; ++j) { \
            int u = 16 * (G) + q4 * 4 + j; \
            if (u < U1c) { \
                float hv = cfc_comb(aA[j] + lb[u], aB[j] + lb[89 + u], aC[j] + lb[178 + u]); \
                half_t hh = (half_t)hv; \
                z1n[135 + u] = hh; z2n[u] = hh; } } } }

// L2 group: 12 MFMA + in-lane combine -> h2^{k-1} + output, gated k>=2
#define L2G(G, F0,F1,F2,F3,F4,F5,F6,F7,F8,F9,F10,F11) { \
    CH4(aA, F0,F1,F2,F3) \
    CH4(aB, F4,F5,F6,F7) \
    CH4(aC, F8,F9,F10,F11) \
    if (wr0 && k >= 2) { \
        _Pragma("unroll") \
        for (int j = 0; j < 4; ++j) { \
            int u = 16 * (G) + q4 * 4 + j; \
            float hv = cfc_comb(aA[j], aB[j], aC[j]); \
            z2n[89 + u] = (half_t)hv; \
            cfb[(size_t)(k - 2) * 32 + u] = hv; } } }

// broadcast B-load (16-lane groups read identical 16B -> LDS broadcast, free)
#define LDB7(ZB) { const half_t* _z = (ZB) + q4 * 8; \
    B0 = *(const uint4v*)(_z);       B1 = *(const uint4v*)(_z + 32); \
    B2 = *(const uint4v*)(_z + 64);  B3 = *(const uint4v*)(_z + 96); \
    B4 = *(const uint4v*)(_z + 128); B5 = *(const uint4v*)(_z + 160); \
    B6 = *(const uint4v*)(_z + 192); }
#define LDB4(ZB) { const half_t* _z = (ZB) + q4 * 8; \
    B0 = *(const uint4v*)(_z);       B1 = *(const uint4v*)(_z + 32); \
    B2 = *(const uint4v*)(_z + 64);  B3 = *(const uint4v*)(_z + 96); }

#define LFi(NM, I) { int _fi = fb + ((I) < nf ? (I) : 0); \
    NM = *(const uint4v*)(Wf + ((size_t)_fi * 512 + lane * 8)); \
    asm volatile("" : "+a"(NM)); }

// ---------------- MFMA scan: 64 blocks x 512 threads, 1 batch/block ---------
// Skewed layer pipeline (verified r8/r13). mod-16-aligned groups: each wave's
// 3 gate tiles put a unit's 3 pre-activations in the SAME lane -> in-register
// combine, no ybuf, ONE barrier per iteration.
__global__ __attribute__((amdgpu_flat_work_group_size(512, 512),
                          amdgpu_waves_per_eu(2, 2)))
void k_scan(const half_t* __restrict__ Wf,
            const float* __restrict__ b1s,
            const float* __restrict__ x,
            const half_t* __restrict__ xh,
            int use_xh,
            float* __restrict__ cfc)
{
    const int t = threadIdx.x;
    const int wid = t >> 6;
    const int lane = t & 63;
    const int q4 = (lane >> 4) & 3;
    const bool wr0 = ((lane & 15) == 0);
    const int b = blockIdx.x;

    __shared__ __align__(16) half_t z0h[2 * 224];   // [x:64|h0@64..198|1@199|0]
    __shared__ __align__(16) half_t z1h[2 * 224];   // [h0:135|h1@135..223]
    __shared__ __align__(16) half_t z2h[2 * 128];   // [h1:89|h2@89..120|1@121|0]
    __shared__ float lb[272];                        // L1 biases (267)

    for (int i = t; i < 448; i += 512) { z0h[i] = (half_t)0.f; z1h[i] = (half_t)0.f; }
    if (t < 256) z2h[t] = (half_t)0.f;
    if (t < 272) lb[t] = (t < 267) ? b1s[t] : 0.f;
    __syncthreads();
    if (t < 2) { z0h[t * 224 + 199] = (half_t)1.f; z2h[t * 128 + 121] = (half_t)1.f; }

    // ---- per-wave frag set: 45 named uint4v pinned to AGPRs ----
    const int fb = (wid < 7) ? wid * 42 : 294;
    const int nf = (wid < 7) ? 42 : 45;
    uint4v f00,f01,f02,f03,f04,f05,f06,f07,f08,f09,f10,f11,f12,f13,f14;
    uint4v f15,f16,f17,f18,f19,f20,f21,f22,f23,f24,f25,f26,f27,f28,f29;
    uint4v f30,f31,f32,f33,f34,f35,f36,f37,f38,f39,f40,f41,f42,f43,f44;
    LFi(f00,0)  LFi(f01,1)  LFi(f02,2)  LFi(f03,3)  LFi(f04,4)  LFi(f05,5)  LFi(f06,6)
    LFi(f07,7)  LFi(f08,8)  LFi(f09,9)  LFi(f10,10) LFi(f11,11) LFi(f12,12) LFi(f13,13)
    LFi(f14,14) LFi(f15,15) LFi(f16,16) LFi(f17,17) LFi(f18,18) LFi(f19,19) LFi(f20,20)
    LFi(f21,21) LFi(f22,22) LFi(f23,23) LFi(f24,24) LFi(f25,25) LFi(f26,26) LFi(f27,27)
    LFi(f28,28) LFi(f29,29) LFi(f30,30) LFi(f31,31) LFi(f32,32) LFi(f33,33) LFi(f34,34)
    LFi(f35,35) LFi(f36,36) LFi(f37,37) LFi(f38,38) LFi(f39,39) LFi(f40,40) LFi(f41,41)
    LFi(f42,42) LFi(f43,43) LFi(f44,44)

    const half_t* xbh = xh + (size_t)b * TTs * DINn;
    const float*  xb  = x  + (size_t)b * TTs * DINn;
    float* cfb = cfc + (size_t)b * TTs * 32;

    auto loadx = [&](int step) -> half_t {
        return use_xh ? xbh[(size_t)step * DINn + lane]
                      : (half_t)xb[(size_t)step * DINn + lane];
    };

    __syncthreads();
    if (t < 64) z0h[t] = use_xh ? xbh[t] : (half_t)xb[t];   // x(0)
    half_t xr = (half_t)0.f;
    if (wid == 7) xr = loadx(1);
    __syncthreads();

    uint4v B0, B1, B2, B3, B4, B5, B6;

#pragma unroll 1
    for (int k = 0; k < TTs + 2; ++k) {
        const int p = k & 1;
        const half_t* z0c = z0h + p * 224;
        const half_t* z1c = z1h + p * 224;
        const half_t* z2c = z2h + p * 128;
        half_t* z0n = z0h + (p ^ 1) * 224;
        half_t* z1n = z1h + (p ^ 1) * 224;
        half_t* z2n = z2h + (p ^ 1) * 128;

        switch (wid) {
        case 0: LDB7(z0c)
            L0G(0, f00,f01,f02,f03,f04,f05,f06,f07,f08,f09,f10,f11,f12,f13,f14,f15,f16,f17,f18,f19,f20)
            L0G(1, f21,f22,f23,f24,f25,f26,f27,f28,f29,f30,f31,f32,f33,f34,f35,f36,f37,f38,f39,f40,f41)
            break;
        case 1: LDB7(z0c)
            L0G(2, f00,f01,f02,f03,f04,f05,f06,f07,f08,f09,f10,f11,f12,f13,f14,f15,f16,f17,f18,f19,f20)
            L0G(3, f21,f22,f23,f24,f25,f26,f27,f28,f29,f30,f31,f32,f33,f34,f35,f36,f37,f38,f39,f40,f41)
            break;
        case 2: LDB7(z0c)
            L0G(4, f00,f01,f02,f03,f04,f05,f06,f07,f08,f09,f10,f11,f12,f13,f14,f15,f16,f17,f18,f19,f20)
            L0G(5, f21,f22,f23,f24,f25,f26,f27,f28,f29,f30,f31,f32,f33,f34,f35,f36,f37,f38,f39,f40,f41)
            break;
        case 3: LDB7(z0c)
            L0G(6, f00,f01,f02,f03,f04,f05,f06,f07,f08,f09,f10,f11,f12,f13,f14,f15,f16,f17,f18,f19,f20)
            L0G(7, f21,f22,f23,f24,f25,f26,f27,f28,f29,f30,f31,f32,f33,f34,f35,f36,f37,f38,f39,f40,f41)
            break;
        case 4: LDB7(z0c)
            L0G(8, f00,f01,f02,f03,f04,f05,f06,f07,f08,f09,f10,f11,f12,f13,f14,f15,f16,f17,f18,f19,f20)
            LDB7(z1c)
            L1G(0, f21,f22,f23,f24,f25,f26,f27,f28,f29,f30,f31,f32,f33,f34,f35,f36,f37,f38,f39,f40,f41)
            break;
        case 5: LDB7(z1c)
            L1G(1, f00,f01,f02,f03,f04,f05,f06,f07,f08,f09,f10,f11,f12,f13,f14,f15,f16,f17,f18,f19,f20)
            L1G(2, f21,f22,f23,f24,f25,f26,f27,f28,f29,f30,f31,f32,f33,f34,f35,f36,f37,f38,f39,f40,f41)
            break;
        case 6: LDB7(z1c)
            L1G(3, f00,f01,f02,f03,f04,f05,f06,f07,f08,f09,f10,f11,f12,f13,f14,f15,f16,f17,f18,f19,f20)
            L1G(4, f21,f22,f23,f24,f25,f26,f27,f28,f29,f30,f31,f32,f33,f34,f35,f36,f37,f38,f39,f40,f41)
            break;
        default: LDB7(z1c)
            L1G(5, f00,f01,f02,f03,f04,f05,f06,f07,f08,f09,f10,f11,f12,f13,f14,f15,f16,f17,f18,f19,f20)
            LDB4(z2c)
            L2G(0, f21,f22,f23,f24,f25,f26,f27,f28,f29,f30,f31,f32)
            L2G(1, f33,f34,f35,f36,f37,f38,f39,f40,f41,f42,f43,f44)
            // x staging: write x(k+1), prefetch x(k+2)
            z0n[lane] = xr;
            { int stn = (k + 2 < TTs) ? (k + 2) : (TTs - 1); xr = loadx(stn); }
            break;
        }
        BAR();
    }
}

// ---------------- head: in-place gelu(cfc@Wh1.T+bh1)@Wh2.T + bh2 ----------------
__global__ __launch_bounds__(256) void k_head(float* io,
                                              const float* __restrict__ Wh1,
                                              const float* __restrict__ bh1,
                                              const float* __restrict__ Wh2T,
                                              const float* __restrict__ bh2)
{
    const int bt = blockIdx.x * 256 + threadIdx.x;
    float c32[32];
    const float4* cp = (const float4*)(io + (size_t)bt * 32);
#pragma unroll
    for (int k = 0; k < 8; ++k) {
        float4 v = cp[k];
        c32[4 * k] = v.x; c32[4 * k + 1] = v.y; c32[4 * k + 2] = v.z; c32[4 * k + 3] = v.w;
    }
    float acc[32];
#pragma unroll
    for (int o = 0; o < 32; ++o) acc[o] = bh2[o];
#pragma unroll 1
    for (int h = 0; h < HPn; ++h) {
        float ss = bh1[h];
        const float* w1r = Wh1 + (size_t)h * 32;
#pragma unroll
        for (int k = 0; k < 32; ++k) ss += c32[k] * w1r[k];
        float g = 0.5f * ss * (1.f + erff(ss * 0.70710678118654752440f));
        const float* w2r = Wh2T + (size_t)h * 32;
#pragma unroll
        for (int o = 0; o < 32; ++o) acc[o] += g * w2r[o];
    }
    float4* op = (float4*)(io + (size_t)bt * 32);
#pragma unroll
    for (int k = 0; k < 8; ++k) {
        float4 v;
        v.x = acc[4 * k]; v.y = acc[4 * k + 1]; v.z = acc[4 * k + 2]; v.w = acc[4 * k + 3];
        op[k] = v;
    }
}

// ---------------- launch ----------------
extern "C" void kernel_launch(void* const* d_in, const int* in_sizes, int n_in,
                              void* d_out, int out_size, void* d_ws, size_t ws_size,
                              hipStream_t stream)
{
    (void)in_sizes; (void)n_in; (void)out_size;
    const float* x      = (const float*)d_in[0];
    const float* Wp     = (const float*)d_in[1];
    const float* bp     = (const float*)d_in[2];
    const float* Wff1_0 = (const float*)d_in[3];
    const float* bff1_0 = (const float*)d_in[4];
    const float* Wff2_0 = (const float*)d_in[5];
    const float* bff2_0 = (const float*)d_in[6];
    const float* Wta_0  = (const float*)d_in[7];
    const float* bta_0  = (const float*)d_in[8];
    const float* Wtb_0  = (const float*)d_in[9];
    const float* btb_0  = (const float*)d_in[10];
    const unsigned char* mask_0 = (const unsigned char*)d_in[11];
    const float* Wff1_1 = (const float*)d_in[12];
    const float* bff1_1 = (const float*)d_in[13];
    const float* Wff2_1 = (const float*)d_in[14];
    const float* bff2_1 = (const float*)d_in[15];
    const float* Wta_1  = (const float*)d_in[16];
    const float* bta_1  = (const float*)d_in[17];
    const float* Wtb_1  = (const float*)d_in[18];
    const float* btb_1  = (const float*)d_in[19];
    const unsigned char* mask_1 = (const unsigned char*)d_in[20];
    const float* Wff1_2 = (const float*)d_in[21];
    const float* bff1_2 = (const float*)d_in[22];
    const float* Wff2_2 = (const float*)d_in[23];
    const float* bff2_2 = (const float*)d_in[24];
    const float* Wta_2  = (const float*)d_in[25];
    const float* bta_2  = (const float*)d_in[26];
    const float* Wtb_2  = (const float*)d_in[27];
    const float* btb_2  = (const float*)d_in[28];
    const unsigned char* mask_2 = (const unsigned char*)d_in[29];
    const float* Wh1    = (const float*)d_in[30];
    const float* bh1    = (const float*)d_in[31];
    const float* Wh2    = (const float*)d_in[32];
    const float* bh2    = (const float*)d_in[33];

    float* ws = (float*)d_ws;
    size_t o = 0;
    float* Wh0s = ws + o; o += (size_t)R0c * U0c;
    float* Wx0s = ws + o; o += (size_t)R0c * HPn;
    float* b0s  = ws + o; o += R0c; o += 3;
    float* Wcb  = ws + o; o += (size_t)R0c * DINn;
    float* b0c  = ws + o; o += R0c; o += 3;
    float* W1s  = ws + o; o += (size_t)R1c * C1c;
    float* b1s  = ws + o; o += R1c; o += 1;
    float* W2s  = ws + o; o += (size_t)R2c * C2c;
    float* b2s  = ws + o; o += R2c;
    float* Wh2T = ws + o; o += (size_t)HPn * 32;
    half_t* W0h = (half_t*)(ws + o); o += (size_t)R0c * 224 / 2;
    half_t* W1h = (half_t*)(ws + o); o += (size_t)R1c * 224 / 2;
    half_t* W2h = (half_t*)(ws + o); o += (size_t)R2c * 128 / 2;
    half_t* Wf  = (half_t*)(ws + o); o += (size_t)NFRAG * 512 / 2;   // A-frags
    // fp16 x stream (16.8 MB) -- only if the workspace is big enough
    half_t* xhp = (half_t*)(ws + o);
    const size_t xh_floats = BTn * (size_t)DINn / 2;
    const int use_xh = (ws_size >= (o + xh_floats) * sizeof(float)) ? 1 : 0;

    k_stack<<<128, 256, 0, stream>>>(Wff1_0, bff1_0, Wff2_0, bff2_0, Wta_0, bta_0, Wtb_0, btb_0,
                                     mask_0, U0c, C0c, HPn, Wx0s, Wh0s, b0s);
    k_stack<<<64, 256, 0, stream>>>(Wff1_1, bff1_1, Wff2_1, bff2_1, Wta_1, bta_1, Wtb_1, btb_1,
                                    mask_1, U1c, C1c, C1c, W1s, W1s, b1s);
    k_stack<<<16, 256, 0, stream>>>(Wff1_2, bff1_2, Wff2_2, bff2_2, Wta_2, bta_2, Wtb_2, btb_2,
                                    mask_2, U2c, C2c, C2c, W2s, W2s, b2s);
    k_comb<<<R0c, DINn, 0, stream>>>(Wx0s, Wp, Wcb);
    k_biasc<<<32, 256, 0, stream>>>(Wx0s, bp, b0s, b0c, Wh2, Wh2T);
    k_pack<<<320, 256, 0, stream>>>(Wcb, Wh0s, W1s, W2s, W0h, W1h, W2h);
    k_frag<<<(NFRAG * 64 + 255) / 256, 256, 0, stream>>>(W0h, W1h, W2h, b0c, b2s, Wf);
    if (use_xh) {
        k_xh<<<(int)(BTn * DINn / 4 / 256), 256, 0, stream>>>(x, xhp);
    }
    k_scan<<<BBn, 512, 0, stream>>>(Wf, b1s, x, xhp, use_xh, (float*)d_out);
    k_head<<<(int)(BTn / 256), 256, 0, stream>>>((float*)d_out, Wh1, bh1, Wh2T, bh2);
}

// Round 16
// 3308.136 us; speedup vs baseline: 2.8985x; 2.8985x over previous
//
#include <hip/hip_runtime.h>
#include <cstdint>
#include <cstddef>

typedef _Float16 half_t;
typedef half_t half2_t __attribute__((ext_vector_type(2)));
typedef _Float16 half8 __attribute__((ext_vector_type(8)));
typedef unsigned uint4v __attribute__((ext_vector_type(4)));
typedef float float4v __attribute__((ext_vector_type(4)));

static constexpr int TTs = 2048;   // timesteps
static constexpr int BBn = 64;     // batch
static constexpr int DINn = 64;    // input dim
static constexpr int HPn  = 256;   // proj dim
static constexpr int U0c = 135, C0c = 391, R0c = 405;   // layer0
static constexpr int U1c = 89,  C1c = 224, R1c = 267;   // layer1
static constexpr int U2c = 32,  C2c = 121, R2c = 96;    // layer2
static constexpr size_t BTn = (size_t)BBn * TTs;        // 131072
static constexpr int NFRAG = 325;                       // 26*7 + 17*7 + 6*4

// ---------------- math helpers ----------------
__device__ __forceinline__ float tanh_f(float x) {
    return 1.f - __fdividef(2.f, __expf(2.f * x) + 1.f);
}
__device__ __forceinline__ float sigm_f(float x) {
    return __fdividef(1.f, 1.f + __expf(-x));
}
__device__ __forceinline__ float cfc_comb(float y0, float y1, float y2) {
    float f1 = tanh_f(y0), f2 = tanh_f(y1), ti = sigm_f(y2);
    return f1 + ti * (f2 - f1);
}

// ---------------- mask dtype probe ----------------
__device__ __forceinline__ int mask_mode(const unsigned char* mp) {
    const unsigned* wp = (const unsigned*)mp;
    bool all01 = true, allf = true;
    for (int k = 0; k < 64; ++k) {
        unsigned w = wp[k];
        all01 = all01 && (w == 0u || w == 1u);
        allf  = allf  && (w == 0u || w == 0x3F800000u);
    }
    if (all01) return 0;
    if (allf)  return 1;
    return 2;
}
__device__ __forceinline__ bool mget(const unsigned char* mp, int mode, int idx) {
    if (mode == 0) return ((const int*)mp)[idx] != 0;
    if (mode == 1) return ((const float*)mp)[idx] != 0.f;
    return mp[idx] != 0;
}

// ---------------- prep: stack + mask weights ----------------
__global__ void k_stack(const float* __restrict__ Wff1, const float* __restrict__ bff1,
                        const float* __restrict__ Wff2, const float* __restrict__ bff2,
                        const float* __restrict__ Wta,  const float* __restrict__ bta,
                        const float* __restrict__ Wtb,  const float* __restrict__ btb,
                        const unsigned char* __restrict__ maskraw,
                        int u, int c, int split,
                        float* __restrict__ outA, float* __restrict__ outB,
                        float* __restrict__ bias_out)
{
    const int mode = mask_mode(maskraw);
    const int total = 3 * u * c + 3 * u;
    for (int idx = blockIdx.x * blockDim.x + threadIdx.x; idx < total;
         idx += gridDim.x * blockDim.x) {
        if (idx < 3 * u * c) {
            int m = idx / (u * c);
            int rem = idx - m * u * c;
            int r = rem / c;
            int k = rem - r * c;
            float v;
            if (m == 2) {
                v = Wta[r * c + k] + Wtb[r * c + k];
            } else {
                bool mk = mget(maskraw, mode, r * c + k);
                float w = (m == 0) ? Wff1[r * c + k] : Wff2[r * c + k];
                v = mk ? w : 0.f;
            }
            int R = m * u + r;
            if (k < split) outA[(size_t)R * split + k] = v;
            else           outB[(size_t)R * (c - split) + (k - split)] = v;
        } else {
            int j = idx - 3 * u * c;
            int m = j / u, r = j - m * u;
            bias_out[j] = (m == 0) ? bff1[r] : ((m == 1) ? bff2[r] : (bta[r] + btb[r]));
        }
    }
}

// ---------------- prep: Wcomb = Wx0s (405x256) @ Wp (256x64) ----------------
__global__ void k_comb(const float* __restrict__ Wx0s, const float* __restrict__ Wp,
                       float* __restrict__ Wcomb)
{
    const int r = blockIdx.x;
    const int d = threadIdx.x;
    float acc = 0.f;
    for (int k = 0; k < HPn; ++k) acc += Wx0s[(size_t)r * HPn + k] * Wp[(size_t)k * DINn + d];
    Wcomb[(size_t)r * DINn + d] = acc;
}

// ---------------- prep: folded bias + Wh2 transpose ----------------
__global__ void k_biasc(const float* __restrict__ Wx0s, const float* __restrict__ bp,
                        const float* __restrict__ b0, float* __restrict__ b0c,
                        const float* __restrict__ Wh2, float* __restrict__ Wh2T)
{
    const int i = blockIdx.x * blockDim.x + threadIdx.x;
    if (i < R0c) {
        float a = b0[i];
        for (int k = 0; k < HPn; ++k) a += Wx0s[(size_t)i * HPn + k] * bp[k];
        b0c[i] = a;
    }
    if (i < HPn * 32) {
        int h = i >> 5, o = i & 31;
        Wh2T[i] = Wh2[(size_t)o * HPn + h];
    }
}

// ---------------- prep: pack weights to padded fp16 row-major ----------------
// W0h (405,224): [Wcb:64 | Wh0s:135 | 0:25]; W1h (267,224); W2h (96,128): [W2s:121|0:7]
__global__ void k_pack(const float* __restrict__ Wcb, const float* __restrict__ Wh0s,
                       const float* __restrict__ W1s, const float* __restrict__ W2s,
                       half_t* __restrict__ W0h, half_t* __restrict__ W1h,
                       half_t* __restrict__ W2h)
{
    const int N0 = R0c * 224, N1 = R1c * 224, N2 = R2c * 128;
    for (int idx = blockIdx.x * blockDim.x + threadIdx.x; idx < N0 + N1 + N2;
         idx += gridDim.x * blockDim.x) {
        if (idx < N0) {
            int r = idx / 224, c = idx - r * 224;
            float v = (c < 64) ? Wcb[(size_t)r * 64 + c]
                               : ((c < 199) ? Wh0s[(size_t)r * 135 + (c - 64)] : 0.f);
            W0h[idx] = (half_t)v;
        } else if (idx < N0 + N1) {
            int i = idx - N0;
            W1h[i] = (half_t)W1s[i];
        } else {
            int i = idx - N0 - N1;
            int r = i / 128, c = i - r * 128;
            W2h[i] = (half_t)((c < 121) ? W2s[(size_t)r * 121 + c] : 0.f);
        }
    }
}

// ---------------- prep: MFMA A-fragment packing (VERIFIED r12/r13) ----------
// Frag f: layer/tile/kk; lane l holds A[row=tile*16+(l&15)][col=kk*32+(l>>4)*8 + j].
// Bias folded into spare K columns: L0 col 199 <- b0c[row]; L2 col 121 <- b2s[row].
__global__ __launch_bounds__(256) void k_frag(const half_t* __restrict__ W0h,
                                              const half_t* __restrict__ W1h,
                                              const half_t* __restrict__ W2h,
                                              const float* __restrict__ b0c,
                                              const float* __restrict__ b2s,
                                              half_t* __restrict__ Wf)
{
    int idx = blockIdx.x * 256 + threadIdx.x;
    if (idx >= NFRAG * 64) return;
    int fid = idx >> 6, l = idx & 63;
    int layer, tile, kk;
    if (fid < 182)      { layer = 0; tile = fid / 7;          kk = fid % 7; }
    else if (fid < 301) { layer = 1; tile = (fid - 182) / 7;  kk = (fid - 182) % 7; }
    else                { layer = 2; tile = (fid - 301) / 4;  kk = (fid - 301) % 4; }
    int row = tile * 16 + (l & 15);
    int c0  = kk * 32 + ((l >> 4) & 3) * 8;
    int nrow  = (layer == 0) ? 405 : ((layer == 1) ? 267 : 96);
    int pitch = (layer == 2) ? 128 : 224;
    const half_t* src = (layer == 0) ? W0h : ((layer == 1) ? W1h : W2h);
    half_t v[8];
#pragma unroll
    for (int j = 0; j < 8; ++j) v[j] = (half_t)0.f;
    if (row < nrow) {
        const half_t* rp = src + (size_t)row * pitch + c0;
#pragma unroll
        for (int j = 0; j < 8; ++j) v[j] = rp[j];
        if (layer == 0 && c0 <= 199 && 199 < c0 + 8) v[199 - c0] = (half_t)b0c[row];
        if (layer == 2 && c0 <= 121 && 121 < c0 + 8) v[121 - c0] = (half_t)b2s[row];
    }
    half_t* dst = Wf + ((size_t)fid * 64 + l) * 8;
#pragma unroll
    for (int j = 0; j < 8; ++j) dst[j] = v[j];
}

// ---------------- prep: x fp32 -> fp16 ----------------
__global__ __launch_bounds__(256) void k_xh(const float* __restrict__ x,
                                            half_t* __restrict__ xh)
{
    size_t i = ((size_t)blockIdx.x * 256 + threadIdx.x) * 4;
    if (i >= BTn * (size_t)DINn) return;
    float4 v = *(const float4*)(x + i);
    half_t* o = xh + i;
    o[0] = (half_t)v.x; o[1] = (half_t)v.y; o[2] = (half_t)v.z; o[3] = (half_t)v.w;
}

// light barrier: LDS-ordering only; vmem stays in flight.
#define BAR() asm volatile("s_waitcnt lgkmcnt(0)\n\ts_barrier" ::: "memory")

// MFMA via the builtin (compiler-managed hazards). Frags pinned to VGPR class
// so A is consumed directly -- no v_accvgpr_read copies.
#define MF(ACC, A, BB) (ACC) = __builtin_amdgcn_mfma_f32_16x16x32_f16( \
    __builtin_bit_cast(half8, (A)), __builtin_bit_cast(half8, (BB)), (ACC), 0, 0, 0);

// col-0 extraction: all 16 N-cols equal (broadcast B) -> lanes 0/16/32/48 store
#define S7(GT, A0,A1,A2,A3,A4,A5,A6) { float4v acc = (float4v)0.0f; \
    MF(acc,A0,B0) MF(acc,A1,B1) MF(acc,A2,B2) MF(acc,A3,B3) \
    MF(acc,A4,B4) MF(acc,A5,B5) MF(acc,A6,B6) \
    if (c0w) *(float4v*)(yv + (GT)*16 + ln4*4) = acc; }
#define S4(GT, A0,A1,A2,A3) { float4v acc = (float4v)0.0f; \
    MF(acc,A0,B0) MF(acc,A1,B1) MF(acc,A2,B2) MF(acc,A3,B3) \
    if (c0w) *(float4v*)(yv + (GT)*16 + ln4*4) = acc; }

// broadcast B-load: every 16-lane group reads the SAME 16B (LDS broadcast, free)
#define LDB7(ZB) { const half_t* _z = (ZB) + ln4*8; \
    B0 = *(const uint4v*)(_z);       B1 = *(const uint4v*)(_z + 32); \
    B2 = *(const uint4v*)(_z + 64);  B3 = *(const uint4v*)(_z + 96); \
    B4 = *(const uint4v*)(_z + 128); B5 = *(const uint4v*)(_z + 160); \
    B6 = *(const uint4v*)(_z + 192); }
#define LDB4(ZB) { const half_t* _z = (ZB) + ln4*8; \
    B0 = *(const uint4v*)(_z);       B1 = *(const uint4v*)(_z + 32); \
    B2 = *(const uint4v*)(_z + 64);  B3 = *(const uint4v*)(_z + 96); }

// pin to VGPR class ("+v"): budget 256/wave at waves_per_eu(2,2); 168 frag
// dwords + ~60 working regs fit -> builtin MFMA reads A directly, zero copies.
#define LFi(NM, I) { int _fi = fb + ((I) < nf ? (I) : 0); \
    NM = *(const uint4v*)(Wf + ((size_t)_fi * 512 + lane * 8)); \
    asm volatile("" : "+v"(NM)); }

// ---------------- MFMA scan: 64 blocks x 512 threads, 1 batch/block ---------
// r13-verbatim structure (verified 2940 us k_scan): skewed layer pipeline,
// broadcast B, linear yv, 2 barriers/iter. Only change vs r13: frag pin class
// "a" -> "v" (removes ~168 v_accvgpr_read VALU instrs per wave-iter).
__global__ __attribute__((amdgpu_flat_work_group_size(512, 512),
                          amdgpu_waves_per_eu(2, 2)))
void k_scan(const half_t* __restrict__ Wf,
            const float* __restrict__ b1s,
            const float* __restrict__ x,
            const half_t* __restrict__ xh,
            int use_xh,
            float* __restrict__ cfc)
{
    const int t = threadIdx.x;
    const int wid = t >> 6;
    const int lane = t & 63;
    const int ln4 = (t >> 4) & 3;
    const bool c0w = ((lane & 15) == 0);
    const int b = blockIdx.x;

    __shared__ __align__(16) half_t z0h[2 * 232];   // [x:64|h0@64..198|1@199|0]
    __shared__ __align__(16) half_t z1h[2 * 232];   // [h0:135|h1@135..223]
    __shared__ __align__(16) half_t z2h[2 * 136];   // [h1:89|h2@89..120|1@121|0]
    __shared__ __align__(16) float  yv[788];        // linear col-0 results

    for (int i = t; i < 464; i += 512) { z0h[i] = (half_t)0.f; z1h[i] = (half_t)0.f; }
    for (int i = t; i < 272; i += 512) z2h[i] = (half_t)0.f;
    __syncthreads();
    if (t < 2) { z0h[t * 232 + 199] = (half_t)1.f; z2h[t * 136 + 121] = (half_t)1.f; }

    // ---- per-wave frag set: 42 named uint4v, VGPR-pinned ----
    const int fb = (wid < 7) ? wid * 42 : 294;
    const int nf = (wid < 7) ? 42 : 31;
    uint4v f00,f01,f02,f03,f04,f05,f06,f07,f08,f09,f10,f11,f12,f13;
    uint4v f14,f15,f16,f17,f18,f19,f20,f21,f22,f23,f24,f25,f26,f27;
    uint4v f28,f29,f30,f31,f32,f33,f34,f35,f36,f37,f38,f39,f40,f41;
    LFi(f00,0)  LFi(f01,1)  LFi(f02,2)  LFi(f03,3)  LFi(f04,4)  LFi(f05,5)  LFi(f06,6)
    LFi(f07,7)  LFi(f08,8)  LFi(f09,9)  LFi(f10,10) LFi(f11,11) LFi(f12,12) LFi(f13,13)
    LFi(f14,14) LFi(f15,15) LFi(f16,16) LFi(f17,17) LFi(f18,18) LFi(f19,19) LFi(f20,20)
    LFi(f21,21) LFi(f22,22) LFi(f23,23) LFi(f24,24) LFi(f25,25) LFi(f26,26) LFi(f27,27)
    LFi(f28,28) LFi(f29,29) LFi(f30,30) LFi(f31,31) LFi(f32,32) LFi(f33,33) LFi(f34,34)
    LFi(f35,35) LFi(f36,36) LFi(f37,37) LFi(f38,38) LFi(f39,39) LFi(f40,40) LFi(f41,41)

    // ---- combine roles: t<135 L0 unit t; 135..223 L1 unit t-135; 224..255 L2 ----
    const int role = (t < 135) ? 0 : ((t < 224) ? 1 : ((t < 256) ? 2 : 3));
    int u = 0;
    float bb0 = 0.f, bb1 = 0.f, bb2 = 0.f;
    if (role == 0) u = t;
    else if (role == 1) { u = t - 135; bb0 = b1s[u]; bb1 = b1s[89 + u]; bb2 = b1s[178 + u]; }
    else if (role == 2) u = t - 224;

    const int xi = t - 256;                 // wave 4 stages x (64 lanes)
    const bool xw = (xi >= 0 && xi < 64);
    const half_t* xbh = xh + (size_t)b * TTs * DINn;
    const float*  xb  = x  + (size_t)b * TTs * DINn;
    float* cfb = cfc + (size_t)b * TTs * 32;

    auto loadx = [&](int step) -> half_t {
        return use_xh ? xbh[(size_t)step * DINn + xi]
                      : (half_t)xb[(size_t)step * DINn + xi];
    };

    __syncthreads();
    half_t xr = (half_t)0.f;
    if (xw) { z0h[xi] = loadx(0); xr = loadx(1); }
    __syncthreads();

    uint4v B0, B1, B2, B3, B4, B5, B6;

#pragma unroll 1
    for (int k = 0; k < TTs + 2; ++k) {
        const int p = k & 1;
        const half_t* z0c = z0h + p * 232;
        const half_t* z1c = z1h + p * 232;
        const half_t* z2c = z2h + p * 136;
        half_t* z0n = z0h + (p ^ 1) * 232;
        half_t* z1n = z1h + (p ^ 1) * 232;
        half_t* z2n = z2h + (p ^ 1) * 136;

        // ============ phase 1: MFMA all tiles -> yv (col 0) ============
        switch (wid) {
        case 0: LDB7(z0c)
            S7(0, f00,f01,f02,f03,f04,f05,f06) S7(1, f07,f08,f09,f10,f11,f12,f13)
            S7(2, f14,f15,f16,f17,f18,f19,f20) S7(3, f21,f22,f23,f24,f25,f26,f27)
            S7(4, f28,f29,f30,f31,f32,f33,f34) S7(5, f35,f36,f37,f38,f39,f40,f41)
            break;
        case 1: LDB7(z0c)
            S7(6, f00,f01,f02,f03,f04,f05,f06) S7(7, f07,f08,f09,f10,f11,f12,f13)
            S7(8, f14,f15,f16,f17,f18,f19,f20) S7(9, f21,f22,f23,f24,f25,f26,f27)
            S7(10,f28,f29,f30,f31,f32,f33,f34) S7(11,f35,f36,f37,f38,f39,f40,f41)
            break;
        case 2: LDB7(z0c)
            S7(12,f00,f01,f02,f03,f04,f05,f06) S7(13,f07,f08,f09,f10,f11,f12,f13)
            S7(14,f14,f15,f16,f17,f18,f19,f20) S7(15,f21,f22,f23,f24,f25,f26,f27)
            S7(16,f28,f29,f30,f31,f32,f33,f34) S7(17,f35,f36,f37,f38,f39,f40,f41)
            break;
        case 3: LDB7(z0c)
            S7(18,f00,f01,f02,f03,f04,f05,f06) S7(19,f07,f08,f09,f10,f11,f12,f13)
            S7(20,f14,f15,f16,f17,f18,f19,f20) S7(21,f21,f22,f23,f24,f25,f26,f27)
            S7(22,f28,f29,f30,f31,f32,f33,f34) S7(23,f35,f36,f37,f38,f39,f40,f41)
            break;
        case 4: LDB7(z0c)
            S7(24, f00,f01,f02,f03,f04,f05,f06) S7(25, f07,f08,f09,f10,f11,f12,f13)
            LDB7(z1c)
            S7(26, f14,f15,f16,f17,f18,f19,f20) S7(27, f21,f22,f23,f24,f25,f26,f27)
            S7(28, f28,f29,f30,f31,f32,f33,f34) S7(29, f35,f36,f37,f38,f39,f40,f41)
            break;
        case 5: LDB7(z1c)
            S7(30,f00,f01,f02,f03,f04,f05,f06) S7(31,f07,f08,f09,f10,f11,f12,f13)
            S7(32,f14,f15,f16,f17,f18,f19,f20) S7(33,f21,f22,f23,f24,f25,f26,f27)
            S7(34,f28,f29,f30,f31,f32,f33,f34) S7(35,f35,f36,f37,f38,f39,f40,f41)
            break;
        case 6: LDB7(z1c)
            S7(36,f00,f01,f02,f03,f04,f05,f06) S7(37,f07,f08,f09,f10,f11,f12,f13)
            S7(38,f14,f15,f16,f17,f18,f19,f20) S7(39,f21,f22,f23,f24,f25,f26,f27)
            S7(40,f28,f29,f30,f31,f32,f33,f34) S7(41,f35,f36,f37,f38,f39,f40,f41)
            break;
        default: LDB7(z1c)
            S7(42, f00,f01,f02,f03,f04,f05,f06)
            LDB4(z2c)
            S4(43, f07,f08,f09,f10) S4(44, f11,f12,f13,f14) S4(45, f15,f16,f17,f18)
            S4(46, f19,f20,f21,f22) S4(47, f23,f24,f25,f26) S4(48, f27,f28,f29,f30)
            break;
        }
        BAR();

        // ============ phase 2: combine yv -> new states ============
        if (role == 0) {
            float hv = cfc_comb(yv[u], yv[135 + u], yv[270 + u]);
            half_t hh = (half_t)hv;
            z0n[64 + u] = hh;
            z1n[u]      = hh;
        } else if (role == 1) {
            float hv = cfc_comb(yv[416 + u] + bb0, yv[505 + u] + bb1, yv[594 + u] + bb2);
            half_t hh = (half_t)hv;
            if (k >= 1) {
                z1n[135 + u] = hh;
                z2n[u]       = hh;
            }
        } else if (role == 2) {
            float hv = cfc_comb(yv[688 + u], yv[720 + u], yv[752 + u]);
            if (k >= 2) {
                z2n[89 + u] = (half_t)hv;
                cfb[(size_t)(k - 2) * 32 + u] = hv;
            }
        }
        if (xw) {
            z0n[xi] = xr;                    // x(k+1)
            int stn = (k + 2 < TTs) ? (k + 2) : (TTs - 1);
            xr = loadx(stn);                 // x(k+2) in flight
        }
        BAR();
    }
}

// ---------------- head: in-place gelu(cfc@Wh1.T+bh1)@Wh2.T + bh2 ----------------
__global__ __launch_bounds__(256) void k_head(float* io,
                                              const float* __restrict__ Wh1,
                                              const float* __restrict__ bh1,
                                              const float* __restrict__ Wh2T,
                                              const float* __restrict__ bh2)
{
    const int bt = blockIdx.x * 256 + threadIdx.x;
    float c32[32];
    const float4* cp = (const float4*)(io + (size_t)bt * 32);
#pragma unroll
    for (int k = 0; k < 8; ++k) {
        float4 v = cp[k];
        c32[4 * k] = v.x; c32[4 * k + 1] = v.y; c32[4 * k + 2] = v.z; c32[4 * k + 3] = v.w;
    }
    float acc[32];
#pragma unroll
    for (int o = 0; o < 32; ++o) acc[o] = bh2[o];
#pragma unroll 1
    for (int h = 0; h < HPn; ++h) {
        float ss = bh1[h];
        const float* w1r = Wh1 + (size_t)h * 32;
#pragma unroll
        for (int k = 0; k < 32; ++k) ss += c32[k] * w1r[k];
        float g = 0.5f * ss * (1.f + erff(ss * 0.70710678118654752440f));
        const float* w2r = Wh2T + (size_t)h * 32;
#pragma unroll
        for (int o = 0; o < 32; ++o) acc[o] += g * w2r[o];
    }
    float4* op = (float4*)(io + (size_t)bt * 32);
#pragma unroll
    for (int k = 0; k < 8; ++k) {
        float4 v;
        v.x = acc[4 * k]; v.y = acc[4 * k + 1]; v.z = acc[4 * k + 2]; v.w = acc[4 * k + 3];
        op[k] = v;
    }
}

// ---------------- launch ----------------
extern "C" void kernel_launch(void* const* d_in, const int* in_sizes, int n_in,
                              void* d_out, int out_size, void* d_ws, size_t ws_size,
                              hipStream_t stream)
{
    (void)in_sizes; (void)n_in; (void)out_size;
    const float* x      = (const float*)d_in[0];
    const float* Wp     = (const float*)d_in[1];
    const float* bp     = (const float*)d_in[2];
    const float* Wff1_0 = (const float*)d_in[3];
    const float* bff1_0 = (const float*)d_in[4];
    const float* Wff2_0 = (const float*)d_in[5];
    const float* bff2_0 = (const float*)d_in[6];
    const float* Wta_0  = (const float*)d_in[7];
    const float* bta_0  = (const float*)d_in[8];
    const float* Wtb_0  = (const float*)d_in[9];
    const float* btb_0  = (const float*)d_in[10];
    const unsigned char* mask_0 = (const unsigned char*)d_in[11];
    const float* Wff1_1 = (const float*)d_in[12];
    const float* bff1_1 = (const float*)d_in[13];
    const float* Wff2_1 = (const float*)d_in[14];
    const float* bff2_1 = (const float*)d_in[15];
    const float* Wta_1  = (const float*)d_in[16];
    const float* bta_1  = (const float*)d_in[17];
    const float* Wtb_1  = (const float*)d_in[18];
    const float* btb_1  = (const float*)d_in[19];
    const unsigned char* mask_1 = (const unsigned char*)d_in[20];
    const float* Wff1_2 = (const float*)d_in[21];
    const float* bff1_2 = (const float*)d_in[22];
    const float* Wff2_2 = (const float*)d_in[23];
    const float* bff2_2 = (const float*)d_in[24];
    const float* Wta_2  = (const float*)d_in[25];
    const float* bta_2  = (const float*)d_in[26];
    const float* Wtb_2  = (const float*)d_in[27];
    const float* btb_2  = (const float*)d_in[28];
    const unsigned char* mask_2 = (const unsigned char*)d_in[29];
    const float* Wh1    = (const float*)d_in[30];
    const float* bh1    = (const float*)d_in[31];
    const float* Wh2    = (const float*)d_in[32];
    const float* bh2    = (const float*)d_in[33];

    float* ws = (float*)d_ws;
    size_t o = 0;
    float* Wh0s = ws + o; o += (size_t)R0c * U0c;
    float* Wx0s = ws + o; o += (size_t)R0c * HPn;
    float* b0s  = ws + o; o += R0c; o += 3;
    float* Wcb  = ws + o; o += (size_t)R0c * DINn;
    float* b0c  = ws + o; o += R0c; o += 3;
    float* W1s  = ws + o; o += (size_t)R1c * C1c;
    float* b1s  = ws + o; o += R1c; o += 1;
    float* W2s  = ws + o; o += (size_t)R2c * C2c;
    float* b2s  = ws + o; o += R2c;
    float* Wh2T = ws + o; o += (size_t)HPn * 32;
    half_t* W0h = (half_t*)(ws + o); o += (size_t)R0c * 224 / 2;
    half_t* W1h = (half_t*)(ws + o); o += (size_t)R1c * 224 / 2;
    half_t* W2h = (half_t*)(ws + o); o += (size_t)R2c * 128 / 2;
    half_t* Wf  = (half_t*)(ws + o); o += (size_t)NFRAG * 512 / 2;   // A-frags
    // fp16 x stream (16.8 MB) -- only if the workspace is big enough
    half_t* xhp = (half_t*)(ws + o);
    const size_t xh_floats = BTn * (size_t)DINn / 2;
    const int use_xh = (ws_size >= (o + xh_floats) * sizeof(float)) ? 1 : 0;

    k_stack<<<128, 256, 0, stream>>>(Wff1_0, bff1_0, Wff2_0, bff2_0, Wta_0, bta_0, Wtb_0, btb_0,
                                     mask_0, U0c, C0c, HPn, Wx0s, Wh0s, b0s);
    k_stack<<<64, 256, 0, stream>>>(Wff1_1, bff1_1, Wff2_1, bff2_1, Wta_1, bta_1, Wtb_1, btb_1,
                                    mask_1, U1c, C1c, C1c, W1s, W1s, b1s);
    k_stack<<<16, 256, 0, stream>>>(Wff1_2, bff1_2, Wff2_2, bff2_2, Wta_2, bta_2, Wtb_2, btb_2,
                                    mask_2, U2c, C2c, C2c, W2s, W2s, b2s);
    k_comb<<<R0c, DINn, 0, stream>>>(Wx0s, Wp, Wcb);
    k_biasc<<<32, 256, 0, stream>>>(Wx0s, bp, b0s, b0c, Wh2, Wh2T);
    k_pack<<<320, 256, 0, stream>>>(Wcb, Wh0s, W1s, W2s, W0h, W1h, W2h);
    k_frag<<<(NFRAG * 64 + 255) / 256, 256, 0, stream>>>(W0h, W1h, W2h, b0c, b2s, Wf);
    if (use_xh) {
        k_xh<<<(int)(BTn * DINn / 4 / 256), 256, 0, stream>>>(x, xhp);
    }
    k_scan<<<BBn, 512, 0, stream>>>(Wf, b1s, x, xhp, use_xh, (float*)d_out);
    k_head<<<(int)(BTn / 256), 256, 0, stream>>>((float*)d_out, Wh1, bh1, Wh2T, bh2);
}

// Round 17
// 2943.228 us; speedup vs baseline: 3.2579x; 1.1240x over previous
//
#include <hip/hip_runtime.h>
#include <cstdint>
#include <cstddef>

typedef _Float16 half_t;
typedef half_t half2_t __attribute__((ext_vector_type(2)));
typedef _Float16 half8 __attribute__((ext_vector_type(8)));
typedef unsigned uint4v __attribute__((ext_vector_type(4)));
typedef float float4v __attribute__((ext_vector_type(4)));

static constexpr int TTs = 2048;   // timesteps
static constexpr int BBn = 64;     // batch
static constexpr int DINn = 64;    // input dim
static constexpr int HPn  = 256;   // proj dim
static constexpr int U0c = 135, C0c = 391, R0c = 405;   // layer0
static constexpr int U1c = 89,  C1c = 224, R1c = 267;   // layer1
static constexpr int U2c = 32,  C2c = 121, R2c = 96;    // layer2
static constexpr size_t BTn = (size_t)BBn * TTs;        // 131072
static constexpr int NFRAG = 339;  // w0-6: 42 each; w7: 45 (21 L1 + 24 L2)

// ---------------- math helpers ----------------
__device__ __forceinline__ float tanh_f(float x) {
    return 1.f - __fdividef(2.f, __expf(2.f * x) + 1.f);
}
__device__ __forceinline__ float sigm_f(float x) {
    return __fdividef(1.f, 1.f + __expf(-x));
}
__device__ __forceinline__ float cfc_comb(float y0, float y1, float y2) {
    float f1 = tanh_f(y0), f2 = tanh_f(y1), ti = sigm_f(y2);
    return f1 + ti * (f2 - f1);
}

// ---------------- mask dtype probe ----------------
__device__ __forceinline__ int mask_mode(const unsigned char* mp) {
    const unsigned* wp = (const unsigned*)mp;
    bool all01 = true, allf = true;
    for (int k = 0; k < 64; ++k) {
        unsigned w = wp[k];
        all01 = all01 && (w == 0u || w == 1u);
        allf  = allf  && (w == 0u || w == 0x3F800000u);
    }
    if (all01) return 0;
    if (allf)  return 1;
    return 2;
}
__device__ __forceinline__ bool mget(const unsigned char* mp, int mode, int idx) {
    if (mode == 0) return ((const int*)mp)[idx] != 0;
    if (mode == 1) return ((const float*)mp)[idx] != 0.f;
    return mp[idx] != 0;
}

// ---------------- prep: stack + mask weights ----------------
__global__ void k_stack(const float* __restrict__ Wff1, const float* __restrict__ bff1,
                        const float* __restrict__ Wff2, const float* __restrict__ bff2,
                        const float* __restrict__ Wta,  const float* __restrict__ bta,
                        const float* __restrict__ Wtb,  const float* __restrict__ btb,
                        const unsigned char* __restrict__ maskraw,
                        int u, int c, int split,
                        float* __restrict__ outA, float* __restrict__ outB,
                        float* __restrict__ bias_out)
{
    const int mode = mask_mode(maskraw);
    const int total = 3 * u * c + 3 * u;
    for (int idx = blockIdx.x * blockDim.x + threadIdx.x; idx < total;
         idx += gridDim.x * blockDim.x) {
        if (idx < 3 * u * c) {
            int m = idx / (u * c);
            int rem = idx - m * u * c;
            int r = rem / c;
            int k = rem - r * c;
            float v;
            if (m == 2) {
                v = Wta[r * c + k] + Wtb[r * c + k];
            } else {
                bool mk = mget(maskraw, mode, r * c + k);
                float w = (m == 0) ? Wff1[r * c + k] : Wff2[r * c + k];
                v = mk ? w : 0.f;
            }
            int R = m * u + r;
            if (k < split) outA[(size_t)R * split + k] = v;
            else           outB[(size_t)R * (c - split) + (k - split)] = v;
        } else {
            int j = idx - 3 * u * c;
            int m = j / u, r = j - m * u;
            bias_out[j] = (m == 0) ? bff1[r] : ((m == 1) ? bff2[r] : (bta[r] + btb[r]));
        }
    }
}

// ---------------- prep: Wcomb = Wx0s (405x256) @ Wp (256x64) ----------------
__global__ void k_comb(const float* __restrict__ Wx0s, const float* __restrict__ Wp,
                       float* __restrict__ Wcomb)
{
    const int r = blockIdx.x;
    const int d = threadIdx.x;
    float acc = 0.f;
    for (int k = 0; k < HPn; ++k) acc += Wx0s[(size_t)r * HPn + k] * Wp[(size_t)k * DINn + d];
    Wcomb[(size_t)r * DINn + d] = acc;
}

// ---------------- prep: folded bias + Wh2 transpose ----------------
__global__ void k_biasc(const float* __restrict__ Wx0s, const float* __restrict__ bp,
                        const float* __restrict__ b0, float* __restrict__ b0c,
                        const float* __restrict__ Wh2, float* __restrict__ Wh2T)
{
    const int i = blockIdx.x * blockDim.x + threadIdx.x;
    if (i < R0c) {
        float a = b0[i];
        for (int k = 0; k < HPn; ++k) a += Wx0s[(size_t)i * HPn + k] * bp[k];
        b0c[i] = a;
    }
    if (i < HPn * 32) {
        int h = i >> 5, o = i & 31;
        Wh2T[i] = Wh2[(size_t)o * HPn + h];
    }
}

// ---------------- prep: pack weights to padded fp16 row-major ----------------
// W0h (405,224): [Wcb:64 | Wh0s:135 | 0:25]; W1h (267,224); W2h (96,128): [W2s:121|0:7]
__global__ void k_pack(const float* __restrict__ Wcb, const float* __restrict__ Wh0s,
                       const float* __restrict__ W1s, const float* __restrict__ W2s,
                       half_t* __restrict__ W0h, half_t* __restrict__ W1h,
                       half_t* __restrict__ W2h)
{
    const int N0 = R0c * 224, N1 = R1c * 224, N2 = R2c * 128;
    for (int idx = blockIdx.x * blockDim.x + threadIdx.x; idx < N0 + N1 + N2;
         idx += gridDim.x * blockDim.x) {
        if (idx < N0) {
            int r = idx / 224, c = idx - r * 224;
            float v = (c < 64) ? Wcb[(size_t)r * 64 + c]
                               : ((c < 199) ? Wh0s[(size_t)r * 135 + (c - 64)] : 0.f);
            W0h[idx] = (half_t)v;
        } else if (idx < N0 + N1) {
            int i = idx - N0;
            W1h[i] = (half_t)W1s[i];
        } else {
            int i = idx - N0 - N1;
            int r = i / 128, c = i - r * 128;
            W2h[i] = (half_t)((c < 121) ? W2s[(size_t)r * 121 + c] : 0.f);
        }
    }
}

// ---------------- prep: MFMA A-fragment packing, mod-16 groups (VERIFIED r14) --
// Wave assignment (42 frags w0-6, 45 w7):
//  w0..w3: L0 groups {2w, 2w+1}; w4: L0 g8 + L1 g0; w5: L1 {1,2}; w6: L1 {3,4};
//  w7: L1 g5 + L2 {0,1}.
// A layout (r12-verified): lane l -> row = 16g + (l&15), col = kk*32 + ((l>>4)&3)*8 + j.
// Bias folded in K: L0 col 199 <- b0c; L2 col 121 <- b2s. L1 bias in combine.
__global__ __launch_bounds__(256) void k_frag(const half_t* __restrict__ W0h,
                                              const half_t* __restrict__ W1h,
                                              const half_t* __restrict__ W2h,
                                              const float* __restrict__ b0c,
                                              const float* __restrict__ b2s,
                                              half_t* __restrict__ Wf)
{
    int idx = blockIdx.x * 256 + threadIdx.x;
    if (idx >= NFRAG * 64) return;
    int fid = idx >> 6, l = idx & 63;
    int mat, g, m, kk;
    if (fid < 294) {
        int w = fid / 42, r = fid - w * 42;
        int gi = r / 21, rr = r - gi * 21;
        m = rr / 7; kk = rr - m * 7;
        if (w < 4)       { mat = 0; g = 2 * w + gi; }
        else if (w == 4) { if (gi == 0) { mat = 0; g = 8; } else { mat = 1; g = 0; } }
        else if (w == 5) { mat = 1; g = 1 + gi; }
        else             { mat = 1; g = 3 + gi; }
    } else {
        int r = fid - 294;
        if (r < 21) { mat = 1; g = 5; m = r / 7; kk = r - m * 7; }
        else { int rr = r - 21; g = rr / 12; int r2 = rr - g * 12; mat = 2;
               m = r2 / 4; kk = r2 - m * 4; }
    }
    int u = 16 * g + (l & 15);
    int c0 = kk * 32 + ((l >> 4) & 3) * 8;
    half_t v[8];
#pragma unroll
    for (int j = 0; j < 8; ++j) v[j] = (half_t)0.f;
    if (mat == 0) {
        if (u < U0c) {
            const half_t* rp = W0h + (size_t)(m * U0c + u) * 224 + c0;
#pragma unroll
            for (int j = 0; j < 8; ++j) v[j] = rp[j];
            if (c0 <= 199 && 199 < c0 + 8) v[199 - c0] = (half_t)b0c[m * U0c + u];
        }
    } else if (mat == 1) {
        if (u < U1c) {
            const half_t* rp = W1h + (size_t)(m * U1c + u) * 224 + c0;
#pragma unroll
            for (int j = 0; j < 8; ++j) v[j] = rp[j];
        }
    } else {
        const half_t* rp = W2h + (size_t)(m * U2c + u) * 128 + c0;
#pragma unroll
        for (int j = 0; j < 8; ++j) v[j] = rp[j];
        if (c0 <= 121 && 121 < c0 + 8) v[121 - c0] = (half_t)b2s[m * U2c + u];
    }
    half_t* dst = Wf + ((size_t)fid * 64 + l) * 8;
#pragma unroll
    for (int j = 0; j < 8; ++j) dst[j] = v[j];
}

// ---------------- prep: x fp32 -> fp16 ----------------
__global__ __launch_bounds__(256) void k_xh(const float* __restrict__ x,
                                            half_t* __restrict__ xh)
{
    size_t i = ((size_t)blockIdx.x * 256 + threadIdx.x) * 4;
    if (i >= BTn * (size_t)DINn) return;
    float4 v = *(const float4*)(x + i);
    half_t* o = xh + i;
    o[0] = (half_t)v.x; o[1] = (half_t)v.y; o[2] = (half_t)v.z; o[3] = (half_t)v.w;
}

// light barrier: LDS-ordering only; vmem stays in flight.
#define BAR() asm volatile("s_waitcnt lgkmcnt(0)\n\ts_barrier" ::: "memory")

#define MF(ACC, A, BB) (ACC) = __builtin_amdgcn_mfma_f32_16x16x32_f16( \
    __builtin_bit_cast(half8, (A)), __builtin_bit_cast(half8, (BB)), (ACC), 0, 0, 0);

// chain C -> per-wave-private yv slot C (no cross-wave sharing -> no barrier)
#define S7C(C, A0,A1,A2,A3,A4,A5,A6) { float4v acc = (float4v)0.0f; \
    MF(acc,A0,B0) MF(acc,A1,B1) MF(acc,A2,B2) MF(acc,A3,B3) \
    MF(acc,A4,B4) MF(acc,A5,B5) MF(acc,A6,B6) \
    if (c0w) *(float4v*)(yw + (C)*16 + ln4*4) = acc; }
#define S4C(C, A0,A1,A2,A3) { float4v acc = (float4v)0.0f; \
    MF(acc,A0,B0) MF(acc,A1,B1) MF(acc,A2,B2) MF(acc,A3,B3) \
    if (c0w) *(float4v*)(yw + (C)*16 + ln4*4) = acc; }

// broadcast B-load (16-lane groups read identical 16B -> LDS broadcast, free)
#define LDB7(ZB) { const half_t* _z = (ZB) + ln4*8; \
    B0 = *(const uint4v*)(_z);       B1 = *(const uint4v*)(_z + 32); \
    B2 = *(const uint4v*)(_z + 64);  B3 = *(const uint4v*)(_z + 96); \
    B4 = *(const uint4v*)(_z + 128); B5 = *(const uint4v*)(_z + 160); \
    B6 = *(const uint4v*)(_z + 192); }
#define LDB4(ZB) { const half_t* _z = (ZB) + ln4*8; \
    B0 = *(const uint4v*)(_z);       B1 = *(const uint4v*)(_z + 32); \
    B2 = *(const uint4v*)(_z + 64);  B3 = *(const uint4v*)(_z + 96); }

#define LFi(NM, I) { int _fi = fb + ((I) < nf ? (I) : 0); \
    NM = *(const uint4v*)(Wf + ((size_t)_fi * 512 + lane * 8)); \
    asm volatile("" : "+a"(NM)); }

// ---------------- MFMA scan: 64 blocks x 512 threads, 1 batch/block ---------
// Single-barrier iteration: each wave owns all 3 gate tiles of its unit groups
// (r14's verified grouping); c0w lanes write chain results to the wave's
// PRIVATE yv slice; same-wave lanes read them back (lgkmcnt-ordered, no
// barrier) and combine on 32-48 lanes/wave. ONE barrier/iter for z handoff.
__global__ __attribute__((amdgpu_flat_work_group_size(512, 512),
                          amdgpu_waves_per_eu(2, 2)))
void k_scan(const half_t* __restrict__ Wf,
            const float* __restrict__ b1s,
            const float* __restrict__ x,
            const half_t* __restrict__ xh,
            int use_xh,
            float* __restrict__ cfc)
{
    const int t = threadIdx.x;
    const int wid = t >> 6;
    const int lane = t & 63;
    const int ln4 = (lane >> 4) & 3;
    const int row = lane & 15;
    const bool c0w = (row == 0);
    const int b = blockIdx.x;

    __shared__ __align__(16) half_t z0h[2 * 232];   // [x:64|h0@64..198|1@199|0]
    __shared__ __align__(16) half_t z1h[2 * 232];   // [h0:135|h1@135..223]
    __shared__ __align__(16) half_t z2h[2 * 136];   // [h1:89|h2@89..120|1@121|0]
    __shared__ __align__(16) float  yv[8 * 144];    // per-wave-private slices

    for (int i = t; i < 464; i += 512) { z0h[i] = (half_t)0.f; z1h[i] = (half_t)0.f; }
    for (int i = t; i < 272; i += 512) z2h[i] = (half_t)0.f;
    __syncthreads();
    if (t < 2) { z0h[t * 232 + 199] = (half_t)1.f; z2h[t * 136 + 121] = (half_t)1.f; }

    float* yw = yv + wid * 144;   // this wave's private yv slice

    // ---- per-wave frag set: up to 45 named uint4v pinned to AGPRs ----
    const int fb = (wid < 7) ? wid * 42 : 294;
    const int nf = (wid < 7) ? 42 : 45;
    uint4v f00,f01,f02,f03,f04,f05,f06,f07,f08,f09,f10,f11,f12,f13,f14;
    uint4v f15,f16,f17,f18,f19,f20,f21,f22,f23,f24,f25,f26,f27,f28,f29;
    uint4v f30,f31,f32,f33,f34,f35,f36,f37,f38,f39,f40,f41,f42,f43,f44;
    LFi(f00,0)  LFi(f01,1)  LFi(f02,2)  LFi(f03,3)  LFi(f04,4)  LFi(f05,5)  LFi(f06,6)
    LFi(f07,7)  LFi(f08,8)  LFi(f09,9)  LFi(f10,10) LFi(f11,11) LFi(f12,12) LFi(f13,13)
    LFi(f14,14) LFi(f15,15) LFi(f16,16) LFi(f17,17) LFi(f18,18) LFi(f19,19) LFi(f20,20)
    LFi(f21,21) LFi(f22,22) LFi(f23,23) LFi(f24,24) LFi(f25,25) LFi(f26,26) LFi(f27,27)
    LFi(f28,28) LFi(f29,29) LFi(f30,30) LFi(f31,31) LFi(f32,32) LFi(f33,33) LFi(f34,34)
    LFi(f35,35) LFi(f36,36) LFi(f37,37) LFi(f38,38) LFi(f39,39) LFi(f40,40) LFi(f41,41)
    LFi(f42,42) LFi(f43,43) LFi(f44,44)

    // ---- combine role (same-wave): 32-48 active lanes per wave ----
    const int gi2 = (lane >> 4) & 1;    // 0/1 within first 32 lanes
    bool cval = false; int clayer = 0, cu = 0, sb = 0;
    float cb0 = 0.f, cb1 = 0.f, cb2 = 0.f;
    if (wid <= 3) {
        if (lane < 32) { cval = true; clayer = 0; cu = 32 * wid + 16 * gi2 + row; sb = gi2 * 3; }
    } else if (wid == 4) {
        if (lane < 16)      { cval = (row < 7); clayer = 0; cu = 128 + row; sb = 0; }
        else if (lane < 32) { cval = true; clayer = 1; cu = row; sb = 3; }
    } else if (wid == 5) {
        if (lane < 32) { cval = true; clayer = 1; cu = 16 + 16 * gi2 + row; sb = gi2 * 3; }
    } else if (wid == 6) {
        if (lane < 32) { cval = true; clayer = 1; cu = 48 + 16 * gi2 + row; sb = gi2 * 3; }
    } else {
        if (lane < 16)      { cval = (row < 9); clayer = 1; cu = 80 + row; sb = 0; }
        else if (lane < 32) { cval = true; clayer = 2; cu = row;      sb = 3; }
        else if (lane < 48) { cval = true; clayer = 2; cu = 16 + row; sb = 6; }
    }
    if (cval && clayer == 1) {
        cb0 = b1s[cu]; cb1 = b1s[89 + cu]; cb2 = b1s[178 + cu];
    }
    const int yb0 = wid * 144 + sb * 16 + row;   // gates at +16, +32

    // x staging: waves 0/1, lanes 32-63
    const bool xw = (wid < 2) && (lane >= 32);
    const int xi = wid * 32 + (lane - 32);
    const half_t* xbh = xh + (size_t)b * TTs * DINn;
    const float*  xb  = x  + (size_t)b * TTs * DINn;
    float* cfb = cfc + (size_t)b * TTs * 32;

    auto loadx = [&](int step) -> half_t {
        return use_xh ? xbh[(size_t)step * DINn + xi]
                      : (half_t)xb[(size_t)step * DINn + xi];
    };

    __syncthreads();
    if (t < 64) z0h[t] = use_xh ? xbh[t] : (half_t)xb[t];   // x(0)
    half_t xr = (half_t)0.f;
    if (xw) xr = loadx(1);
    __syncthreads();

    uint4v B0, B1, B2, B3, B4, B5, B6;

#pragma unroll 1
    for (int k = 0; k < TTs + 2; ++k) {
        const int p = k & 1;
        const half_t* z0c = z0h + p * 232;
        const half_t* z1c = z1h + p * 232;
        const half_t* z2c = z2h + p * 136;
        half_t* z0n = z0h + (p ^ 1) * 232;
        half_t* z1n = z1h + (p ^ 1) * 232;
        half_t* z2n = z2h + (p ^ 1) * 136;

        // ===== phase 1: MFMA chains -> private yv (no barrier after) =====
        switch (wid) {
        case 0: case 1: case 2: case 3: LDB7(z0c)
            S7C(0, f00,f01,f02,f03,f04,f05,f06) S7C(1, f07,f08,f09,f10,f11,f12,f13)
            S7C(2, f14,f15,f16,f17,f18,f19,f20) S7C(3, f21,f22,f23,f24,f25,f26,f27)
            S7C(4, f28,f29,f30,f31,f32,f33,f34) S7C(5, f35,f36,f37,f38,f39,f40,f41)
            break;
        case 4: LDB7(z0c)
            S7C(0, f00,f01,f02,f03,f04,f05,f06) S7C(1, f07,f08,f09,f10,f11,f12,f13)
            S7C(2, f14,f15,f16,f17,f18,f19,f20)
            LDB7(z1c)
            S7C(3, f21,f22,f23,f24,f25,f26,f27) S7C(4, f28,f29,f30,f31,f32,f33,f34)
            S7C(5, f35,f36,f37,f38,f39,f40,f41)
            break;
        case 5: case 6: LDB7(z1c)
            S7C(0, f00,f01,f02,f03,f04,f05,f06) S7C(1, f07,f08,f09,f10,f11,f12,f13)
            S7C(2, f14,f15,f16,f17,f18,f19,f20) S7C(3, f21,f22,f23,f24,f25,f26,f27)
            S7C(4, f28,f29,f30,f31,f32,f33,f34) S7C(5, f35,f36,f37,f38,f39,f40,f41)
            break;
        default: LDB7(z1c)
            S7C(0, f00,f01,f02,f03,f04,f05,f06) S7C(1, f07,f08,f09,f10,f11,f12,f13)
            S7C(2, f14,f15,f16,f17,f18,f19,f20)
            LDB4(z2c)
            S4C(3, f21,f22,f23,f24) S4C(4, f25,f26,f27,f28) S4C(5, f29,f30,f31,f32)
            S4C(6, f33,f34,f35,f36) S4C(7, f37,f38,f39,f40) S4C(8, f41,f42,f43,f44)
            break;
        }

        // ===== phase 2: same-wave combine (lgkmcnt-ordered, no barrier) =====
        if (cval) {
            float y0 = yv[yb0], y1 = yv[yb0 + 16], y2 = yv[yb0 + 32];
            float hv = cfc_comb(y0 + cb0, y1 + cb1, y2 + cb2);
            half_t hh = (half_t)hv;
            if (clayer == 0) {
                z0n[64 + cu] = hh;
                z1n[cu]      = hh;
            } else if (clayer == 1) {
                if (k >= 1) { z1n[135 + cu] = hh; z2n[cu] = hh; }
            } else {
                if (k >= 2) {
                    z2n[89 + cu] = hh;
                    cfb[(size_t)(k - 2) * 32 + cu] = hv;
                }
            }
        }
        if (xw) {
            z0n[xi] = xr;                    // x(k+1)
            int stn = (k + 2 < TTs) ? (k + 2) : (TTs - 1);
            xr = loadx(stn);                 // x(k+2) in flight
        }
        BAR();   // single barrier: z-buffer handoff for next iteration
    }
}

// ---------------- head: in-place gelu(cfc@Wh1.T+bh1)@Wh2.T + bh2 ----------------
__global__ __launch_bounds__(256) void k_head(float* io,
                                              const float* __restrict__ Wh1,
                                              const float* __restrict__ bh1,
                                              const float* __restrict__ Wh2T,
                                              const float* __restrict__ bh2)
{
    const int bt = blockIdx.x * 256 + threadIdx.x;
    float c32[32];
    const float4* cp = (const float4*)(io + (size_t)bt * 32);
#pragma unroll
    for (int k = 0; k < 8; ++k) {
        float4 v = cp[k];
        c32[4 * k] = v.x; c32[4 * k + 1] = v.y; c32[4 * k + 2] = v.z; c32[4 * k + 3] = v.w;
    }
    float acc[32];
#pragma unroll
    for (int o = 0; o < 32; ++o) acc[o] = bh2[o];
#pragma unroll 1
    for (int h = 0; h < HPn; ++h) {
        float ss = bh1[h];
        const float* w1r = Wh1 + (size_t)h * 32;
#pragma unroll
        for (int k = 0; k < 32; ++k) ss += c32[k] * w1r[k];
        float g = 0.5f * ss * (1.f + erff(ss * 0.70710678118654752440f));
        const float* w2r = Wh2T + (size_t)h * 32;
#pragma unroll
        for (int o = 0; o < 32; ++o) acc[o] += g * w2r[o];
    }
    float4* op = (float4*)(io + (size_t)bt * 32);
#pragma unroll
    for (int k = 0; k < 8; ++k) {
        float4 v;
        v.x = acc[4 * k]; v.y = acc[4 * k + 1]; v.z = acc[4 * k + 2]; v.w = acc[4 * k + 3];
        op[k] = v;
    }
}

// ---------------- launch ----------------
extern "C" void kernel_launch(void* const* d_in, const int* in_sizes, int n_in,
                              void* d_out, int out_size, void* d_ws, size_t ws_size,
                              hipStream_t stream)
{
    (void)in_sizes; (void)n_in; (void)out_size;
    const float* x      = (const float*)d_in[0];
    const float* Wp     = (const float*)d_in[1];
    const float* bp     = (const float*)d_in[2];
    const float* Wff1_0 = (const float*)d_in[3];
    const float* bff1_0 = (const float*)d_in[4];
    const float* Wff2_0 = (const float*)d_in[5];
    const float* bff2_0 = (const float*)d_in[6];
    const float* Wta_0  = (const float*)d_in[7];
    const float* bta_0  = (const float*)d_in[8];
    const float* Wtb_0  = (const float*)d_in[9];
    const float* btb_0  = (const float*)d_in[10];
    const unsigned char* mask_0 = (const unsigned char*)d_in[11];
    const float* Wff1_1 = (const float*)d_in[12];
    const float* bff1_1 = (const float*)d_in[13];
    const float* Wff2_1 = (const float*)d_in[14];
    const float* bff2_1 = (const float*)d_in[15];
    const float* Wta_1  = (const float*)d_in[16];
    const float* bta_1  = (const float*)d_in[17];
    const float* Wtb_1  = (const float*)d_in[18];
    const float* btb_1  = (const float*)d_in[19];
    const unsigned char* mask_1 = (const unsigned char*)d_in[20];
    const float* Wff1_2 = (const float*)d_in[21];
    const float* bff1_2 = (const float*)d_in[22];
    const float* Wff2_2 = (const float*)d_in[23];
    const float* bff2_2 = (const float*)d_in[24];
    const float* Wta_2  = (const float*)d_in[25];
    const float* bta_2  = (const float*)d_in[26];
    const float* Wtb_2  = (const float*)d_in[27];
    const float* btb_2  = (const float*)d_in[28];
    const unsigned char* mask_2 = (const unsigned char*)d_in[29];
    const float* Wh1    = (const float*)d_in[30];
    const float* bh1    = (const float*)d_in[31];
    const float* Wh2    = (const float*)d_in[32];
    const float* bh2    = (const float*)d_in[33];

    float* ws = (float*)d_ws;
    size_t o = 0;
    float* Wh0s = ws + o; o += (size_t)R0c * U0c;
    float* Wx0s = ws + o; o += (size_t)R0c * HPn;
    float* b0s  = ws + o; o += R0c; o += 3;
    float* Wcb  = ws + o; o += (size_t)R0c * DINn;
    float* b0c  = ws + o; o += R0c; o += 3;
    float* W1s  = ws + o; o += (size_t)R1c * C1c;
    float* b1s  = ws + o; o += R1c; o += 1;
    float* W2s  = ws + o; o += (size_t)R2c * C2c;
    float* b2s  = ws + o; o += R2c;
    float* Wh2T = ws + o; o += (size_t)HPn * 32;
    half_t* W0h = (half_t*)(ws + o); o += (size_t)R0c * 224 / 2;
    half_t* W1h = (half_t*)(ws + o); o += (size_t)R1c * 224 / 2;
    half_t* W2h = (half_t*)(ws + o); o += (size_t)R2c * 128 / 2;
    half_t* Wf  = (half_t*)(ws + o); o += (size_t)NFRAG * 512 / 2;   // A-frags
    // fp16 x stream (16.8 MB) -- only if the workspace is big enough
    half_t* xhp = (half_t*)(ws + o);
    const size_t xh_floats = BTn * (size_t)DINn / 2;
    const int use_xh = (ws_size >= (o + xh_floats) * sizeof(float)) ? 1 : 0;

    k_stack<<<128, 256, 0, stream>>>(Wff1_0, bff1_0, Wff2_0, bff2_0, Wta_0, bta_0, Wtb_0, btb_0,
                                     mask_0, U0c, C0c, HPn, Wx0s, Wh0s, b0s);
    k_stack<<<64, 256, 0, stream>>>(Wff1_1, bff1_1, Wff2_1, bff2_1, Wta_1, bta_1, Wtb_1, btb_1,
                                    mask_1, U1c, C1c, C1c, W1s, W1s, b1s);
    k_stack<<<16, 256, 0, stream>>>(Wff1_2, bff1_2, Wff2_2, bff2_2, Wta_2, bta_2, Wtb_2, btb_2,
                                    mask_2, U2c, C2c, C2c, W2s, W2s, b2s);
    k_comb<<<R0c, DINn, 0, stream>>>(Wx0s, Wp, Wcb);
    k_biasc<<<32, 256, 0, stream>>>(Wx0s, bp, b0s, b0c, Wh2, Wh2T);
    k_pack<<<320, 256, 0, stream>>>(Wcb, Wh0s, W1s, W2s, W0h, W1h, W2h);
    k_frag<<<(NFRAG * 64 + 255) / 256, 256, 0, stream>>>(W0h, W1h, W2h, b0c, b2s, Wf);
    if (use_xh) {
        k_xh<<<(int)(BTn * DINn / 4 / 256), 256, 0, stream>>>(x, xhp);
    }
    k_scan<<<BBn, 512, 0, stream>>>(Wf, b1s, x, xhp, use_xh, (float*)d_out);
    k_head<<<(int)(BTn / 256), 256, 0, stream>>>((float*)d_out, Wh1, bh1, Wh2T, bh2);
}